// Round 15
// baseline (338.321 us; speedup 1.0000x reference)
//
#include <hip/hip_runtime.h>
#include <stdint.h>

// SimpleRNN fused kernel for MI355X (gfx950).
// B=256, T=512, I=64, H=256, O=1, fp32.
//
// History (key points):
// R1: padded-LDS conflict fix 608->461us. R7: multi-j (J=4/S=8) ->319us.
// R11: gfx950 VALU cannot read AGPR operands (proven by compile error).
// R12-R14: full-asm recurrence, weights pinned in clobbered v64-v223
//     (tax gone), DPP reduce + fine lgkmcnt -> 321.6us. Counters: VALU
//     ~960cyc/step (pk_fma ~4cyc), LDS pipe ~96 instr/CU/step is the
//     dominant non-VALU term.
// R15: halve LDS instructions: J=8/S=16 mapping. Lane (g=l>>4,s=l&15)
//     owns j0=32w+8g..+7 x k=16s..16s+15. Same 160 weight floats, same
//     80 pk_fma, but 5 front ds_reads/lane (4 h + 1 x) vs 10.
//     LDS/CU/step: 96 -> 56 instr. Reduce: 4 levels -- xor1/xor2 DPP
//     quad_perm, xor4 ds_swizzle 0x101F, xor8 DPP row_ror:8 (R8-verified).
//     h layout slot(k)=k+4*(k>>4) (80B/lane-seg stride): front reads
//     2-way bank (free, m136). x rows 256B: 2-way. Writes <=2-way.

#define RNN_B 256
#define RNN_T 512
#define RNN_I 64
#define RNN_H 256

// ---- one step: h from RD (4xb128) + x from v55 (1xb128) -> h_new to WR.
// v0-15 h, v16-19 x, v20-35 acc pairs (jj=0..7), v36-43 p, v44-47 red
// temps, v52-54 tanh temps, v55 x addr.
// wh[jj] 16 floats at v[64+16jj..79+16jj]; wi[jj] 4 floats at v[192+4jj..].
#define STEP(RD, WR) \
  "ds_read_b128 v[0:3], "   RD " offset:0\n\t" \
  "ds_read_b128 v[4:7], "   RD " offset:16\n\t" \
  "ds_read_b128 v[8:11], "  RD " offset:32\n\t" \
  "ds_read_b128 v[12:15], " RD " offset:48\n\t" \
  "ds_read_b128 v[16:19], v55 offset:0\n\t" \
  "v_add_u32 v55, 0x100, v55\n\t" \
  "s_waitcnt lgkmcnt(4)\n\t" \
  "v_pk_mul_f32 v[20:21], v[0:1], v[64:65]\n\t" \
  "v_pk_mul_f32 v[22:23], v[0:1], v[80:81]\n\t" \
  "v_pk_mul_f32 v[24:25], v[0:1], v[96:97]\n\t" \
  "v_pk_mul_f32 v[26:27], v[0:1], v[112:113]\n\t" \
  "v_pk_mul_f32 v[28:29], v[0:1], v[128:129]\n\t" \
  "v_pk_mul_f32 v[30:31], v[0:1], v[144:145]\n\t" \
  "v_pk_mul_f32 v[32:33], v[0:1], v[160:161]\n\t" \
  "v_pk_mul_f32 v[34:35], v[0:1], v[176:177]\n\t" \
  "v_pk_fma_f32 v[20:21], v[2:3], v[66:67], v[20:21]\n\t" \
  "v_pk_fma_f32 v[22:23], v[2:3], v[82:83], v[22:23]\n\t" \
  "v_pk_fma_f32 v[24:25], v[2:3], v[98:99], v[24:25]\n\t" \
  "v_pk_fma_f32 v[26:27], v[2:3], v[114:115], v[26:27]\n\t" \
  "v_pk_fma_f32 v[28:29], v[2:3], v[130:131], v[28:29]\n\t" \
  "v_pk_fma_f32 v[30:31], v[2:3], v[146:147], v[30:31]\n\t" \
  "v_pk_fma_f32 v[32:33], v[2:3], v[162:163], v[32:33]\n\t" \
  "v_pk_fma_f32 v[34:35], v[2:3], v[178:179], v[34:35]\n\t" \
  "s_waitcnt lgkmcnt(3)\n\t" \
  "v_pk_fma_f32 v[20:21], v[4:5], v[68:69], v[20:21]\n\t" \
  "v_pk_fma_f32 v[22:23], v[4:5], v[84:85], v[22:23]\n\t" \
  "v_pk_fma_f32 v[24:25], v[4:5], v[100:101], v[24:25]\n\t" \
  "v_pk_fma_f32 v[26:27], v[4:5], v[116:117], v[26:27]\n\t" \
  "v_pk_fma_f32 v[28:29], v[4:5], v[132:133], v[28:29]\n\t" \
  "v_pk_fma_f32 v[30:31], v[4:5], v[148:149], v[30:31]\n\t" \
  "v_pk_fma_f32 v[32:33], v[4:5], v[164:165], v[32:33]\n\t" \
  "v_pk_fma_f32 v[34:35], v[4:5], v[180:181], v[34:35]\n\t" \
  "v_pk_fma_f32 v[20:21], v[6:7], v[70:71], v[20:21]\n\t" \
  "v_pk_fma_f32 v[22:23], v[6:7], v[86:87], v[22:23]\n\t" \
  "v_pk_fma_f32 v[24:25], v[6:7], v[102:103], v[24:25]\n\t" \
  "v_pk_fma_f32 v[26:27], v[6:7], v[118:119], v[26:27]\n\t" \
  "v_pk_fma_f32 v[28:29], v[6:7], v[134:135], v[28:29]\n\t" \
  "v_pk_fma_f32 v[30:31], v[6:7], v[150:151], v[30:31]\n\t" \
  "v_pk_fma_f32 v[32:33], v[6:7], v[166:167], v[32:33]\n\t" \
  "v_pk_fma_f32 v[34:35], v[6:7], v[182:183], v[34:35]\n\t" \
  "s_waitcnt lgkmcnt(2)\n\t" \
  "v_pk_fma_f32 v[20:21], v[8:9], v[72:73], v[20:21]\n\t" \
  "v_pk_fma_f32 v[22:23], v[8:9], v[88:89], v[22:23]\n\t" \
  "v_pk_fma_f32 v[24:25], v[8:9], v[104:105], v[24:25]\n\t" \
  "v_pk_fma_f32 v[26:27], v[8:9], v[120:121], v[26:27]\n\t" \
  "v_pk_fma_f32 v[28:29], v[8:9], v[136:137], v[28:29]\n\t" \
  "v_pk_fma_f32 v[30:31], v[8:9], v[152:153], v[30:31]\n\t" \
  "v_pk_fma_f32 v[32:33], v[8:9], v[168:169], v[32:33]\n\t" \
  "v_pk_fma_f32 v[34:35], v[8:9], v[184:185], v[34:35]\n\t" \
  "v_pk_fma_f32 v[20:21], v[10:11], v[74:75], v[20:21]\n\t" \
  "v_pk_fma_f32 v[22:23], v[10:11], v[90:91], v[22:23]\n\t" \
  "v_pk_fma_f32 v[24:25], v[10:11], v[106:107], v[24:25]\n\t" \
  "v_pk_fma_f32 v[26:27], v[10:11], v[122:123], v[26:27]\n\t" \
  "v_pk_fma_f32 v[28:29], v[10:11], v[138:139], v[28:29]\n\t" \
  "v_pk_fma_f32 v[30:31], v[10:11], v[154:155], v[30:31]\n\t" \
  "v_pk_fma_f32 v[32:33], v[10:11], v[170:171], v[32:33]\n\t" \
  "v_pk_fma_f32 v[34:35], v[10:11], v[186:187], v[34:35]\n\t" \
  "s_waitcnt lgkmcnt(1)\n\t" \
  "v_pk_fma_f32 v[20:21], v[12:13], v[76:77], v[20:21]\n\t" \
  "v_pk_fma_f32 v[22:23], v[12:13], v[92:93], v[22:23]\n\t" \
  "v_pk_fma_f32 v[24:25], v[12:13], v[108:109], v[24:25]\n\t" \
  "v_pk_fma_f32 v[26:27], v[12:13], v[124:125], v[26:27]\n\t" \
  "v_pk_fma_f32 v[28:29], v[12:13], v[140:141], v[28:29]\n\t" \
  "v_pk_fma_f32 v[30:31], v[12:13], v[156:157], v[30:31]\n\t" \
  "v_pk_fma_f32 v[32:33], v[12:13], v[172:173], v[32:33]\n\t" \
  "v_pk_fma_f32 v[34:35], v[12:13], v[188:189], v[34:35]\n\t" \
  "v_pk_fma_f32 v[20:21], v[14:15], v[78:79], v[20:21]\n\t" \
  "v_pk_fma_f32 v[22:23], v[14:15], v[94:95], v[22:23]\n\t" \
  "v_pk_fma_f32 v[24:25], v[14:15], v[110:111], v[24:25]\n\t" \
  "v_pk_fma_f32 v[26:27], v[14:15], v[126:127], v[26:27]\n\t" \
  "v_pk_fma_f32 v[28:29], v[14:15], v[142:143], v[28:29]\n\t" \
  "v_pk_fma_f32 v[30:31], v[14:15], v[158:159], v[30:31]\n\t" \
  "v_pk_fma_f32 v[32:33], v[14:15], v[174:175], v[32:33]\n\t" \
  "v_pk_fma_f32 v[34:35], v[14:15], v[190:191], v[34:35]\n\t" \
  "s_waitcnt lgkmcnt(0)\n\t" \
  "v_pk_fma_f32 v[20:21], v[16:17], v[192:193], v[20:21]\n\t" \
  "v_pk_fma_f32 v[22:23], v[16:17], v[196:197], v[22:23]\n\t" \
  "v_pk_fma_f32 v[24:25], v[16:17], v[200:201], v[24:25]\n\t" \
  "v_pk_fma_f32 v[26:27], v[16:17], v[204:205], v[26:27]\n\t" \
  "v_pk_fma_f32 v[28:29], v[16:17], v[208:209], v[28:29]\n\t" \
  "v_pk_fma_f32 v[30:31], v[16:17], v[212:213], v[30:31]\n\t" \
  "v_pk_fma_f32 v[32:33], v[16:17], v[216:217], v[32:33]\n\t" \
  "v_pk_fma_f32 v[34:35], v[16:17], v[220:221], v[34:35]\n\t" \
  "v_pk_fma_f32 v[20:21], v[18:19], v[194:195], v[20:21]\n\t" \
  "v_pk_fma_f32 v[22:23], v[18:19], v[198:199], v[22:23]\n\t" \
  "v_pk_fma_f32 v[24:25], v[18:19], v[202:203], v[24:25]\n\t" \
  "v_pk_fma_f32 v[26:27], v[18:19], v[206:207], v[26:27]\n\t" \
  "v_pk_fma_f32 v[28:29], v[18:19], v[210:211], v[28:29]\n\t" \
  "v_pk_fma_f32 v[30:31], v[18:19], v[214:215], v[30:31]\n\t" \
  "v_pk_fma_f32 v[32:33], v[18:19], v[218:219], v[32:33]\n\t" \
  "v_pk_fma_f32 v[34:35], v[18:19], v[222:223], v[34:35]\n\t" \
  /* horizontal: p_jj = acc.x + acc.y */ \
  "v_add_f32 v36, v20, v21\n\t" \
  "v_add_f32 v37, v22, v23\n\t" \
  "v_add_f32 v38, v24, v25\n\t" \
  "v_add_f32 v39, v26, v27\n\t" \
  "v_add_f32 v40, v28, v29\n\t" \
  "v_add_f32 v41, v30, v31\n\t" \
  "v_add_f32 v42, v32, v33\n\t" \
  "v_add_f32 v43, v34, v35\n\t" \
  /* L1 xor1 (jj bit0), DPP quad_perm[1,0,3,2] */ \
  "v_cndmask_b32 v44, v37, v36, %[m1]\n\t" \
  "v_cndmask_b32 v36, v36, v37, %[m1]\n\t" \
  "v_cndmask_b32 v45, v39, v38, %[m1]\n\t" \
  "v_cndmask_b32 v38, v38, v39, %[m1]\n\t" \
  "v_cndmask_b32 v46, v41, v40, %[m1]\n\t" \
  "v_cndmask_b32 v40, v40, v41, %[m1]\n\t" \
  "v_cndmask_b32 v47, v43, v42, %[m1]\n\t" \
  "v_cndmask_b32 v42, v42, v43, %[m1]\n\t" \
  "s_nop 1\n\t" \
  "v_mov_b32_dpp v44, v44 quad_perm:[1,0,3,2] row_mask:0xf bank_mask:0xf\n\t" \
  "v_mov_b32_dpp v45, v45 quad_perm:[1,0,3,2] row_mask:0xf bank_mask:0xf\n\t" \
  "v_mov_b32_dpp v46, v46 quad_perm:[1,0,3,2] row_mask:0xf bank_mask:0xf\n\t" \
  "v_mov_b32_dpp v47, v47 quad_perm:[1,0,3,2] row_mask:0xf bank_mask:0xf\n\t" \
  "v_add_f32 v36, v36, v44\n\t" \
  "v_add_f32 v38, v38, v45\n\t" \
  "v_add_f32 v40, v40, v46\n\t" \
  "v_add_f32 v42, v42, v47\n\t" \
  /* L2 xor2 (jj bit1), DPP quad_perm[2,3,0,1] */ \
  "v_cndmask_b32 v44, v38, v36, %[m2]\n\t" \
  "v_cndmask_b32 v36, v36, v38, %[m2]\n\t" \
  "v_cndmask_b32 v45, v42, v40, %[m2]\n\t" \
  "v_cndmask_b32 v40, v40, v42, %[m2]\n\t" \
  "s_nop 1\n\t" \
  "v_mov_b32_dpp v44, v44 quad_perm:[2,3,0,1] row_mask:0xf bank_mask:0xf\n\t" \
  "v_mov_b32_dpp v45, v45 quad_perm:[2,3,0,1] row_mask:0xf bank_mask:0xf\n\t" \
  "v_add_f32 v36, v36, v44\n\t" \
  "v_add_f32 v40, v40, v45\n\t" \
  /* L3 xor4 (jj bit2), ds_swizzle */ \
  "v_cndmask_b32 v44, v40, v36, %[m4]\n\t" \
  "v_cndmask_b32 v36, v36, v40, %[m4]\n\t" \
  "ds_swizzle_b32 v44, v44 offset:0x101F\n\t" \
  "s_waitcnt lgkmcnt(0)\n\t" \
  "v_add_f32 v36, v36, v44\n\t" \
  /* L4 xor8 (k-halves), DPP row_ror:8 */ \
  "s_nop 1\n\t" \
  "v_mov_b32_dpp v44, v36 row_ror:8 row_mask:0xf bank_mask:0xf\n\t" \
  "v_add_f32 v36, v36, v44\n\t" \
  /* bias + tanh */ \
  "v_add_f32 v36, %[bias], v36\n\t" \
  "v_max_f32 v36, %[klo], v36\n\t" \
  "v_min_f32 v36, %[khi], v36\n\t" \
  "v_mul_f32 v36, %[km], v36\n\t" \
  "v_exp_f32 v53, v36\n\t" \
  "s_nop 1\n\t" \
  "v_subrev_f32 v54, 1.0, v53\n\t" \
  "v_add_f32 v53, 1.0, v53\n\t" \
  "v_rcp_f32 v53, v53\n\t" \
  "s_nop 1\n\t" \
  "v_mul_f32 v54, v54, v53\n\t" \
  "v_mov_b32 %[hj], v54\n\t" \
  "ds_write_b32 " WR ", v54\n\t" \
  "s_waitcnt lgkmcnt(0)\n\t" \
  "s_barrier\n\t"

__global__
__attribute__((amdgpu_flat_work_group_size(512, 512), amdgpu_waves_per_eu(2, 2)))
void rnn_fused_kernel(const float* __restrict__ x,     // [B,T,I]
                      const float* __restrict__ W_ih,  // [H,I]
                      const float* __restrict__ W_hh,  // [H,H]
                      const float* __restrict__ b_ih,  // [H]
                      const float* __restrict__ b_hh,  // [H]
                      const float* __restrict__ fc_W,  // [O,H], O=1
                      const float* __restrict__ fc_b,  // [O]
                      float* __restrict__ out)         // [B,O]
{
    const int b   = blockIdx.x;
    const int tid = threadIdx.x;    // 0..511
    const int w   = tid >> 6;       // wave 0..7
    const int l   = tid & 63;       // lane
    const int g   = l >> 4;         // j-octet within wave, 0..3
    const int s   = l & 15;         // k-segment, 0..15
    const int j0  = w * 32 + g * 8; // first j of this lane's octet

    __shared__ float hbuf[2][384];     // padded h (slot(j)=j+4*(j>>4), max 315)
                                       // + dummy slots 320..351
    __shared__ float xt[32][RNN_I];    // x tile: 32 timesteps, 8 KB
    __shared__ float red[8];

    // lane finalizes j_fin = j0 + (s&7) after the 4-level reduce-scatter
    const int   j_fin = j0 + (s & 7);
    const int   jslot = j_fin + 4 * (j_fin >> 4);
    const int   wslot = (s < 8) ? jslot : (320 + (l & 31)); // dummy for s>=8
    const float bias2 = b_ih[j_fin] + b_hh[j_fin];
    const float fcw   = fc_W[j_fin];

    // LDS byte addresses
    const uint32_t hb   = (uint32_t)(uintptr_t)&hbuf[0][0];
    const uint32_t xtb  = (uint32_t)(uintptr_t)&xt[0][0];
    const uint32_t hrd0 = hb + 80u * (uint32_t)s;          // k=16s -> byte 80s
    const uint32_t hrd1 = hb + 1536u + 80u * (uint32_t)s;
    const uint32_t hwr0 = hb + 4u * (uint32_t)wslot;
    const uint32_t hwr1 = hb + 1536u + 4u * (uint32_t)wslot;
    const uint32_t xst  = xtb + 256u * (uint32_t)(tid >> 4) + 16u * (uint32_t)(tid & 15);
    const uint32_t xrd0 = xtb + 16u * (uint32_t)s;

    const unsigned long long m1 = __ballot(l & 1);
    const unsigned long long m2 = __ballot(l & 2);
    const unsigned long long m4 = __ballot(l & 4);

    // global pointers
    const float* whp = W_hh + (size_t)j0 * RNN_H + 16 * s;
    const float* wip = W_ih + (size_t)j0 * RNN_I + 4 * s;
    const float* xgp = x + (size_t)b * RNN_T * RNN_I + 4 * tid;
    const uint32_t whlo = (uint32_t)(uintptr_t)whp, whhi = (uint32_t)((uintptr_t)whp >> 32);
    const uint32_t wilo = (uint32_t)(uintptr_t)wip, wihi = (uint32_t)((uintptr_t)wip >> 32);
    const uint32_t xglo = (uint32_t)(uintptr_t)xgp, xghi = (uint32_t)((uintptr_t)xgp >> 32);

    // prologue: h0 = 0 (covers real slots 0..315 and dummies)
    if (tid < 384) hbuf[0][tid] = 0.0f;
    __syncthreads();

    float hj = 0.0f;
    int cntt, cnts, sadv;
    const float khi = 10.0f, klo = -10.0f, km = 2.8853900817779268f;

    asm volatile(
        // ---- weights -> v64..v223 (once). wh jj=0..3 from base, jj=4..7
        // from base+4096 (offset immediate must stay < 4096).
        "v_mov_b32 v56, %[whlo]\n\t"
        "v_mov_b32 v57, %[whhi]\n\t"
        "v_add_co_u32 v58, vcc, 0x1000, v56\n\t"
        "v_addc_co_u32 v59, vcc, 0, v57, vcc\n\t"
        "global_load_dwordx4 v[64:67],   v[56:57], off\n\t"
        "global_load_dwordx4 v[68:71],   v[56:57], off offset:16\n\t"
        "global_load_dwordx4 v[72:75],   v[56:57], off offset:32\n\t"
        "global_load_dwordx4 v[76:79],   v[56:57], off offset:48\n\t"
        "global_load_dwordx4 v[80:83],   v[56:57], off offset:1024\n\t"
        "global_load_dwordx4 v[84:87],   v[56:57], off offset:1040\n\t"
        "global_load_dwordx4 v[88:91],   v[56:57], off offset:1056\n\t"
        "global_load_dwordx4 v[92:95],   v[56:57], off offset:1072\n\t"
        "global_load_dwordx4 v[96:99],   v[56:57], off offset:2048\n\t"
        "global_load_dwordx4 v[100:103], v[56:57], off offset:2064\n\t"
        "global_load_dwordx4 v[104:107], v[56:57], off offset:2080\n\t"
        "global_load_dwordx4 v[108:111], v[56:57], off offset:2096\n\t"
        "global_load_dwordx4 v[112:115], v[56:57], off offset:3072\n\t"
        "global_load_dwordx4 v[116:119], v[56:57], off offset:3088\n\t"
        "global_load_dwordx4 v[120:123], v[56:57], off offset:3104\n\t"
        "global_load_dwordx4 v[124:127], v[56:57], off offset:3120\n\t"
        "global_load_dwordx4 v[128:131], v[58:59], off\n\t"
        "global_load_dwordx4 v[132:135], v[58:59], off offset:16\n\t"
        "global_load_dwordx4 v[136:139], v[58:59], off offset:32\n\t"
        "global_load_dwordx4 v[140:143], v[58:59], off offset:48\n\t"
        "global_load_dwordx4 v[144:147], v[58:59], off offset:1024\n\t"
        "global_load_dwordx4 v[148:151], v[58:59], off offset:1040\n\t"
        "global_load_dwordx4 v[152:155], v[58:59], off offset:1056\n\t"
        "global_load_dwordx4 v[156:159], v[58:59], off offset:1072\n\t"
        "global_load_dwordx4 v[160:163], v[58:59], off offset:2048\n\t"
        "global_load_dwordx4 v[164:167], v[58:59], off offset:2064\n\t"
        "global_load_dwordx4 v[168:171], v[58:59], off offset:2080\n\t"
        "global_load_dwordx4 v[172:175], v[58:59], off offset:2096\n\t"
        "global_load_dwordx4 v[176:179], v[58:59], off offset:3072\n\t"
        "global_load_dwordx4 v[180:183], v[58:59], off offset:3088\n\t"
        "global_load_dwordx4 v[184:187], v[58:59], off offset:3104\n\t"
        "global_load_dwordx4 v[188:191], v[58:59], off offset:3120\n\t"
        "v_mov_b32 v56, %[wilo]\n\t"
        "v_mov_b32 v57, %[wihi]\n\t"
        "global_load_dwordx4 v[192:195], v[56:57], off\n\t"
        "global_load_dwordx4 v[196:199], v[56:57], off offset:256\n\t"
        "global_load_dwordx4 v[200:203], v[56:57], off offset:512\n\t"
        "global_load_dwordx4 v[204:207], v[56:57], off offset:768\n\t"
        "global_load_dwordx4 v[208:211], v[56:57], off offset:1024\n\t"
        "global_load_dwordx4 v[212:215], v[56:57], off offset:1280\n\t"
        "global_load_dwordx4 v[216:219], v[56:57], off offset:1536\n\t"
        "global_load_dwordx4 v[220:223], v[56:57], off offset:1792\n\t"
        // ---- x prefetch pipeline (v58:59 addr, v60:63 data) ----
        "v_mov_b32 v58, %[xglo]\n\t"
        "v_mov_b32 v59, %[xghi]\n\t"
        "global_load_dwordx4 v[60:63], v[58:59], off\n\t"
        "v_add_co_u32 v58, vcc, 0x2000, v58\n\t"
        "v_addc_co_u32 v59, vcc, 0, v59, vcc\n\t"
        "s_mov_b32 %[cntt], 16\n\t"
        "LTILE%=:\n\t"
        "s_waitcnt vmcnt(0)\n\t"
        "ds_write_b128 %[xst], v[60:63]\n\t"
        "global_load_dwordx4 v[60:63], v[58:59], off\n\t"
        // stop ADVANCING at cntt==2: the final (dead) load re-reads tile15
        // instead of stepping past the end of x (R13 fix).
        "s_cmp_lg_u32 %[cntt], 2\n\t"
        "s_cselect_b32 %[sadv], 0x2000, 0\n\t"
        "v_add_co_u32 v58, vcc, %[sadv], v58\n\t"
        "v_addc_co_u32 v59, vcc, 0, v59, vcc\n\t"
        "v_mov_b32 v55, %[xrd0]\n\t"
        "s_waitcnt lgkmcnt(0)\n\t"
        "s_barrier\n\t"
        "s_mov_b32 %[cnts], 16\n\t"
        "LSTEP%=:\n\t"
        STEP("%[hrd0]", "%[hwr1]")
        STEP("%[hrd1]", "%[hwr0]")
        "s_sub_u32 %[cnts], %[cnts], 1\n\t"
        "s_cmp_lg_u32 %[cnts], 0\n\t"
        "s_cbranch_scc1 LSTEP%=\n\t"
        "s_sub_u32 %[cntt], %[cntt], 1\n\t"
        "s_cmp_lg_u32 %[cntt], 0\n\t"
        "s_cbranch_scc1 LTILE%=\n\t"
        // drain the final (dead) x load (R13 fix).
        "s_waitcnt vmcnt(0)\n\t"
        : [hj] "+v"(hj), [cntt] "=&s"(cntt), [cnts] "=&s"(cnts), [sadv] "=&s"(sadv)
        : [whlo] "v"(whlo), [whhi] "v"(whhi), [wilo] "v"(wilo), [wihi] "v"(wihi),
          [xglo] "v"(xglo), [xghi] "v"(xghi), [xst] "v"(xst), [xrd0] "v"(xrd0),
          [hrd0] "v"(hrd0), [hrd1] "v"(hrd1), [hwr0] "v"(hwr0), [hwr1] "v"(hwr1),
          [bias] "v"(bias2),
          [m1] "s"(m1), [m2] "s"(m2), [m4] "s"(m4),
          [khi] "s"(khi), [klo] "s"(klo), [km] "s"(km)
        : "memory", "vcc", "scc",
          "v0","v1","v2","v3","v4","v5","v6","v7","v8","v9",
          "v10","v11","v12","v13","v14","v15","v16","v17","v18","v19",
          "v20","v21","v22","v23","v24","v25","v26","v27","v28","v29",
          "v30","v31","v32","v33","v34","v35","v36","v37","v38","v39",
          "v40","v41","v42","v43","v44","v45","v46","v47","v48","v49",
          "v50","v51","v52","v53","v54","v55","v56","v57","v58","v59",
          "v60","v61","v62","v63","v64","v65","v66","v67","v68","v69",
          "v70","v71","v72","v73","v74","v75","v76","v77","v78","v79",
          "v80","v81","v82","v83","v84","v85","v86","v87","v88","v89",
          "v90","v91","v92","v93","v94","v95","v96","v97","v98","v99",
          "v100","v101","v102","v103","v104","v105","v106","v107","v108","v109",
          "v110","v111","v112","v113","v114","v115","v116","v117","v118","v119",
          "v120","v121","v122","v123","v124","v125","v126","v127","v128","v129",
          "v130","v131","v132","v133","v134","v135","v136","v137","v138","v139",
          "v140","v141","v142","v143","v144","v145","v146","v147","v148","v149",
          "v150","v151","v152","v153","v154","v155","v156","v157","v158","v159",
          "v160","v161","v162","v163","v164","v165","v166","v167","v168","v169",
          "v170","v171","v172","v173","v174","v175","v176","v177","v178","v179",
          "v180","v181","v182","v183","v184","v185","v186","v187","v188","v189",
          "v190","v191","v192","v193","v194","v195","v196","v197","v198","v199",
          "v200","v201","v202","v203","v204","v205","v206","v207","v208","v209",
          "v210","v211","v212","v213","v214","v215","v216","v217","v218","v219",
          "v220","v221","v222","v223");

    // ---- epilogue: out[b] = sum_j h_T[j]*fc_W[j] + fc_b ----
    float term = (s < 8) ? hj * fcw : 0.0f;   // each j counted once
    #pragma unroll
    for (int d = 1; d < 64; d <<= 1) term += __shfl_xor(term, d, 64);
    if (l == 0) red[w] = term;
    __syncthreads();
    if (tid == 0) {
        float sum = 0.f;
        #pragma unroll
        for (int ww = 0; ww < 8; ++ww) sum += red[ww];
        out[b] = sum + fc_b[0];
    }
}

extern "C" void kernel_launch(void* const* d_in, const int* in_sizes, int n_in,
                              void* d_out, int out_size, void* d_ws, size_t ws_size,
                              hipStream_t stream) {
    const float* x    = (const float*)d_in[0];
    const float* W_ih = (const float*)d_in[1];
    const float* W_hh = (const float*)d_in[2];
    const float* b_ih = (const float*)d_in[3];
    const float* b_hh = (const float*)d_in[4];
    const float* fc_W = (const float*)d_in[5];
    const float* fc_b = (const float*)d_in[6];
    float* out = (float*)d_out;

    rnn_fused_kernel<<<RNN_B, 512, 0, stream>>>(x, W_ih, W_hh, b_ih, b_hh, fc_W, fc_b, out);
}